// Round 2
// baseline (2476.791 us; speedup 1.0000x reference)
//
#include <hip/hip_runtime.h>
#include <hip/hip_bf16.h>
#include <stdint.h>

// Problem constants
#define B_    8
#define MD    1024   // MODEL_DIM
#define HD    2048   // HIGH_DIM
#define T_    4096
#define KEEP_ 64
#define CAP   96     // per-column nnz capacity (mean 32; P(>96) ~ 1e-18)
#define BAND  2e-4f  // top-k boundary band half-width (>> max fp32 GEMM error)

// ---------------------------------------------------------------------------
// Kernel 1: transpose W_c [MD][HD] f32 -> W_cT [HD][MD] bf16 (L2-resident 4MB)
// ---------------------------------------------------------------------------
__global__ void k_transpose_wc(const float* __restrict__ Wc,
                               __hip_bfloat16* __restrict__ WcT) {
    __shared__ float s[32][33];
    const int d0 = blockIdx.x * 32;
    const int m0 = blockIdx.y * 32;
    const int tx = threadIdx.x;   // 0..31
    const int ty = threadIdx.y;   // 0..7
    #pragma unroll
    for (int k = 0; k < 4; k++) {
        s[ty + k * 8][tx] = Wc[(size_t)(m0 + ty + k * 8) * HD + d0 + tx];
    }
    __syncthreads();
    #pragma unroll
    for (int k = 0; k < 4; k++) {
        WcT[(size_t)(d0 + ty + k * 8) * MD + m0 + tx] =
            __float2bfloat16(s[tx][ty + k * 8]);
    }
}

// ---------------------------------------------------------------------------
// Kernel 2: expand GEMM  y[b,d,t] = sum_c We[d,c] * x[b,c,t] + be[d]
// fp32 VALU SGEMM: 128x128 block tile, BK=8, 256 threads, 8x8 microtile
// ---------------------------------------------------------------------------
__launch_bounds__(256)
__global__ void k_gemm_expand(const float* __restrict__ x,
                              const float* __restrict__ We,
                              const float* __restrict__ be,
                              float* __restrict__ y) {
    __shared__ __align__(16) float As[8][128];
    __shared__ __align__(16) float Bs[8][128];

    const int t0  = blockIdx.x * 128;
    const int d0  = blockIdx.y * 128;
    const int b   = blockIdx.z;
    const int tid = threadIdx.x;
    const int tx  = tid & 15;
    const int ty  = tid >> 4;

    const float* xb = x + (size_t)b * MD * T_;

    const int a_dd = tid >> 1, a_k4 = (tid & 1) * 4;   // A loader
    const int b_kk = tid >> 5, b_t4 = (tid & 31) * 4;  // B loader

    float4 a_reg = *(const float4*)&We[(size_t)(d0 + a_dd) * MD + a_k4];
    float4 b_reg = *(const float4*)&xb[(size_t)b_kk * T_ + t0 + b_t4];

    float acc[2][2][4][4];
    #pragma unroll
    for (int p = 0; p < 2; p++)
        #pragma unroll
        for (int q = 0; q < 2; q++)
            #pragma unroll
            for (int i = 0; i < 4; i++)
                #pragma unroll
                for (int j = 0; j < 4; j++) acc[p][q][i][j] = 0.f;

    for (int k0 = 0; k0 < MD; k0 += 8) {
        As[a_k4 + 0][a_dd] = a_reg.x;
        As[a_k4 + 1][a_dd] = a_reg.y;
        As[a_k4 + 2][a_dd] = a_reg.z;
        As[a_k4 + 3][a_dd] = a_reg.w;
        *(float4*)&Bs[b_kk][b_t4] = b_reg;
        __syncthreads();
        if (k0 + 8 < MD) {  // register prefetch of next K-tile
            a_reg = *(const float4*)&We[(size_t)(d0 + a_dd) * MD + (k0 + 8) + a_k4];
            b_reg = *(const float4*)&xb[(size_t)(k0 + 8 + b_kk) * T_ + t0 + b_t4];
        }
        #pragma unroll
        for (int kk = 0; kk < 8; kk++) {
            float4 a0 = *(const float4*)&As[kk][ty * 4];
            float4 a1 = *(const float4*)&As[kk][64 + ty * 4];
            float4 b0 = *(const float4*)&Bs[kk][tx * 4];
            float4 b1 = *(const float4*)&Bs[kk][64 + tx * 4];
            const float av[2][4] = {{a0.x, a0.y, a0.z, a0.w}, {a1.x, a1.y, a1.z, a1.w}};
            const float bv[2][4] = {{b0.x, b0.y, b0.z, b0.w}, {b1.x, b1.y, b1.z, b1.w}};
            #pragma unroll
            for (int p = 0; p < 2; p++)
                #pragma unroll
                for (int i = 0; i < 4; i++)
                    #pragma unroll
                    for (int q = 0; q < 2; q++)
                        #pragma unroll
                        for (int j = 0; j < 4; j++)
                            acc[p][q][i][j] = fmaf(av[p][i], bv[q][j], acc[p][q][i][j]);
        }
        __syncthreads();
    }

    float* yb = y + (size_t)b * HD * T_;
    #pragma unroll
    for (int p = 0; p < 2; p++) {
        #pragma unroll
        for (int i = 0; i < 4; i++) {
            const int d = d0 + p * 64 + ty * 4 + i;
            const float bias = be[d];
            #pragma unroll
            for (int q = 0; q < 2; q++) {
                float4 v;
                v.x = acc[p][q][i][0] + bias;
                v.y = acc[p][q][i][1] + bias;
                v.z = acc[p][q][i][2] + bias;
                v.w = acc[p][q][i][3] + bias;
                *(float4*)&yb[(size_t)d * T_ + t0 + q * 64 + tx * 4] = v;
            }
        }
    }
}

// ---------------------------------------------------------------------------
// Kernel 3: exact top-64 per row of 4096. fp32 radix-select for the 64th
// value, then fp64 refinement of the boundary band so the selection matches
// the exact (reference) ordering even where fp32 rounding differs.
// Tie-break lowest index (lax.top_k). In-place sparsify + build per-(b,t)
// column lists of (d, val) for the contraction.
// ---------------------------------------------------------------------------
__launch_bounds__(256)
__global__ void k_topk(float* __restrict__ y,
                       const float* __restrict__ x,
                       const float* __restrict__ We,
                       const float* __restrict__ be,
                       int* __restrict__ colcnt, float2* __restrict__ collist) {
    __shared__ __align__(16) uint32_t su[T_];
    __shared__ double s_red[256];
    __shared__ double s_cand_val[64];
    __shared__ int    s_cand_idx[64];
    __shared__ unsigned char s_cand_keep[64];
    __shared__ int hist[16];
    __shared__ int s_bcast[2];
    __shared__ int s_nc, s_nhi;

    const int row = blockIdx.x;
    const int b   = row >> 11;     // row / 2048
    const int d   = row & 2047;
    const int tid = threadIdx.x;
    float* yrow = y + (size_t)row * T_;

    // load row, map float -> order-preserving uint
    #pragma unroll
    for (int j = 0; j < 4; j++) {
        const int i4 = j * 256 + tid;           // float4 index
        float4 v = *(const float4*)&yrow[i4 * 4];
        uint4 u;
        const uint32_t* pv = (const uint32_t*)&v;
        uint32_t* pu = (uint32_t*)&u;
        #pragma unroll
        for (int e = 0; e < 4; e++) {
            const uint32_t f = pv[e];
            pu[e] = (f & 0x80000000u) ? ~f : (f | 0x80000000u);
        }
        *(uint4*)&su[i4 * 4] = u;
    }

    // MSB-first 4-bit radix select of the KEEP-th largest key
    uint32_t prefix = 0;
    int need = KEEP_;
    for (int shift = 28; shift >= 0; shift -= 4) {
        if (tid < 16) hist[tid] = 0;
        __syncthreads();
        #pragma unroll
        for (int j = 0; j < 16; j++) {
            const uint32_t u = su[j * 256 + tid];
            const uint32_t hi = (shift == 28) ? 0u : (u >> (shift + 4));
            if (hi == prefix) atomicAdd(&hist[(u >> shift) & 15], 1);
        }
        __syncthreads();
        if (tid == 0) {
            int cum = 0, chosen = 15;
            for (int bkt = 15; bkt >= 0; bkt--) {
                if (cum + hist[bkt] >= need) { chosen = bkt; break; }
                cum += hist[bkt];
            }
            s_bcast[0] = chosen;
            s_bcast[1] = need - cum;
        }
        __syncthreads();
        prefix = (prefix << 4) | (uint32_t)s_bcast[0];
        need = s_bcast[1];
    }
    // decode 64th-largest key -> float
    const uint32_t Vu = prefix;
    const uint32_t Vb = (Vu & 0x80000000u) ? (Vu & 0x7FFFFFFFu) : ~Vu;
    const float Vf = __uint_as_float(Vb);
    const float hi_thr = Vf + BAND;
    const float lo_thr = Vf - BAND;

    // classify: > hi_thr definitely kept; [lo_thr, hi_thr] are candidates
    if (tid == 0) { s_nc = 0; s_nhi = 0; }
    __syncthreads();
    #pragma unroll
    for (int j = 0; j < 16; j++) {
        const int i = j * 256 + tid;
        const uint32_t u = su[i];
        const uint32_t fb = (u & 0x80000000u) ? (u & 0x7FFFFFFFu) : ~u;
        const float f = __uint_as_float(fb);
        if (f > hi_thr) {
            atomicAdd(&s_nhi, 1);
        } else if (f >= lo_thr) {
            const int p = atomicAdd(&s_nc, 1);
            if (p < 64) s_cand_idx[p] = i;
        }
    }
    __syncthreads();
    const int nc    = min(s_nc, 64);
    const int slots = KEEP_ - s_nhi;   // always >= 1, and nc >= slots

    if (nc > slots) {
        // true near-tie: recompute candidate y in fp64 and rank exactly
        for (int j = 0; j < nc; j++) {
            const int t = s_cand_idx[j];
            double partial = 0.0;
            for (int c = tid; c < MD; c += 256)
                partial += (double)We[(size_t)d * MD + c] *
                           (double)x[((size_t)b * MD + c) * T_ + t];
            s_red[tid] = partial;
            __syncthreads();
            for (int off = 128; off > 0; off >>= 1) {
                if (tid < off) s_red[tid] += s_red[tid + off];
                __syncthreads();
            }
            if (tid == 0) s_cand_val[j] = s_red[0] + (double)be[d];
            __syncthreads();
        }
        if (tid < nc) {
            const double v = s_cand_val[tid];
            const int    ti = s_cand_idx[tid];
            int rank = 0;
            for (int j = 0; j < nc; j++) {
                if (j == tid) continue;
                if (s_cand_val[j] > v ||
                    (s_cand_val[j] == v && s_cand_idx[j] < ti)) rank++;
            }
            s_cand_keep[tid] = (rank < slots) ? 1 : 0;
        }
    } else {
        if (tid < nc) s_cand_keep[tid] = 1;  // all candidates fit
    }
    __syncthreads();

    // write back sparse row + scatter kept entries into column lists
    #pragma unroll
    for (int j = 0; j < 16; j++) {
        const int i = j * 256 + tid;
        const uint32_t u = su[i];
        const uint32_t fb = (u & 0x80000000u) ? (u & 0x7FFFFFFFu) : ~u;
        const float f = __uint_as_float(fb);
        bool keep;
        if (f > hi_thr) {
            keep = true;
        } else if (f < lo_thr) {
            keep = false;
        } else {
            keep = false;
            for (int q = 0; q < nc; q++)
                if (s_cand_idx[q] == i) { keep = (s_cand_keep[q] != 0); break; }
        }
        if (keep) {
            const int col = b * T_ + i;
            const int pos = atomicAdd(&colcnt[col], 1);
            if (pos < CAP)
                collist[(size_t)col * CAP + pos] = make_float2(__int_as_float(d), f);
            yrow[i] = f;
        } else {
            yrow[i] = 0.0f;
        }
    }
}

// ---------------------------------------------------------------------------
// Kernel 4: sparse contract  out[b,m,t] = bc[m] + sum_nnz val * WcT[d][m]
// ---------------------------------------------------------------------------
__launch_bounds__(256)
__global__ void k_contract(const int* __restrict__ colcnt,
                           const float2* __restrict__ collist,
                           const __hip_bfloat16* __restrict__ WcT,
                           const float* __restrict__ bc,
                           float* __restrict__ out) {
    __shared__ float2 s_list[16][CAP];
    __shared__ int    s_cnt[16];
    __shared__ float  s_t[256][17];

    const int t0  = blockIdx.x * 16;
    const int b   = blockIdx.y;
    const int tid = threadIdx.x;

    if (tid < 16) s_cnt[tid] = min(colcnt[b * T_ + t0 + tid], CAP);
    __syncthreads();
    for (int c = 0; c < 16; c++) {
        const int n = s_cnt[c];
        for (int i = tid; i < n; i += 256)
            s_list[c][i] = collist[(size_t)(b * T_ + t0 + c) * CAP + i];
    }
    __syncthreads();

    for (int mc = 0; mc < 4; mc++) {
        const int m = mc * 256 + tid;
        const float bias = bc[m];
        float acc[16];
        #pragma unroll
        for (int c = 0; c < 16; c++) acc[c] = bias;

        for (int c = 0; c < 16; c++) {
            const int n = s_cnt[c];
            for (int i = 0; i < n; i++) {
                const float2 e = s_list[c][i];
                const int dd = __float_as_int(e.x);
                const float w = __bfloat162float(WcT[(size_t)dd * MD + m]);
                acc[c] = fmaf(e.y, w, acc[c]);
            }
        }

        #pragma unroll
        for (int c = 0; c < 16; c++) s_t[tid][c] = acc[c];
        __syncthreads();
        #pragma unroll
        for (int pass = 0; pass < 4; pass++) {
            const int r  = pass * 64 + (tid >> 2);
            const int cj = (tid & 3) * 4;
            float4 v;
            v.x = s_t[r][cj + 0];
            v.y = s_t[r][cj + 1];
            v.z = s_t[r][cj + 2];
            v.w = s_t[r][cj + 3];
            const int m_out = mc * 256 + r;
            *(float4*)&out[((size_t)b * MD + m_out) * T_ + t0 + cj] = v;
        }
        __syncthreads();
    }
}

// ---------------------------------------------------------------------------
extern "C" void kernel_launch(void* const* d_in, const int* in_sizes, int n_in,
                              void* d_out, int out_size, void* d_ws, size_t ws_size,
                              hipStream_t stream) {
    const float* x  = (const float*)d_in[0];   // [B, MD, T]
    const float* We = (const float*)d_in[1];   // [HD, MD]
    const float* be = (const float*)d_in[2];   // [HD]
    const float* Wc = (const float*)d_in[3];   // [MD, HD]
    const float* bc = (const float*)d_in[4];   // [MD]

    float* out0 = (float*)d_out;                        // out    [B, MD, T]
    float* out1 = out0 + (size_t)B_ * MD * T_;          // sparse [B, HD, T]

    // workspace layout: colcnt (128KB) | collist (24MB) | WcT bf16 (4MB)
    char* ws = (char*)d_ws;
    int*     colcnt  = (int*)ws;
    float2*  collist = (float2*)(ws + (size_t)B_ * T_ * sizeof(int));
    __hip_bfloat16* WcT =
        (__hip_bfloat16*)(ws + (size_t)B_ * T_ * sizeof(int) +
                          (size_t)B_ * T_ * CAP * sizeof(float2));

    hipMemsetAsync(colcnt, 0, (size_t)B_ * T_ * sizeof(int), stream);

    k_transpose_wc<<<dim3(HD / 32, MD / 32), dim3(32, 8), 0, stream>>>(Wc, WcT);
    k_gemm_expand<<<dim3(T_ / 128, HD / 128, B_), 256, 0, stream>>>(x, We, be, out1);
    k_topk<<<B_ * HD, 256, 0, stream>>>(out1, x, We, be, colcnt, collist);
    k_contract<<<dim3(T_ / 16, B_), 256, 0, stream>>>(colcnt, collist, WcT, bc, out0);
}

// Round 3
// 1532.886 us; speedup vs baseline: 1.6158x; 1.6158x over previous
//
#include <hip/hip_runtime.h>
#include <hip/hip_bf16.h>
#include <stdint.h>

// Problem constants
#define B_    8
#define MD    1024   // MODEL_DIM
#define HD    2048   // HIGH_DIM
#define T_    4096
#define KEEP_ 64
#define CAP   96     // per-column nnz capacity (mean 32; P(>96) ~ 1e-18)
#define BAND  2e-4f  // top-k boundary band half-width (>> split-bf16 GEMM error ~1e-5)

typedef __attribute__((ext_vector_type(8))) short short8;
typedef __attribute__((ext_vector_type(4))) float f32x4;

// async global->LDS, 16B per lane (wave-uniform LDS base + lane*16)
__device__ __forceinline__ void gload_lds16(const void* g, void* l) {
    __builtin_amdgcn_global_load_lds(
        (const __attribute__((address_space(1))) uint32_t*)g,
        (__attribute__((address_space(3))) uint32_t*)l, 16, 0, 0);
}

__device__ __forceinline__ void split1(float a, short& h, short& l) {
    __hip_bfloat16 bh = __float2bfloat16(a);
    float r = a - __bfloat162float(bh);
    __hip_bfloat16 bl = __float2bfloat16(r);
    h = *(short*)&bh;
    l = *(short*)&bl;
}

// ---------------------------------------------------------------------------
// Kernel 1: transpose W_c [MD][HD] f32 -> W_cT [HD][MD] bf16 (L2-resident 4MB)
// ---------------------------------------------------------------------------
__global__ void k_transpose_wc(const float* __restrict__ Wc,
                               __hip_bfloat16* __restrict__ WcT) {
    __shared__ float s[32][33];
    const int d0 = blockIdx.x * 32;
    const int m0 = blockIdx.y * 32;
    const int tx = threadIdx.x;   // 0..31
    const int ty = threadIdx.y;   // 0..7
    #pragma unroll
    for (int k = 0; k < 4; k++)
        s[ty + k * 8][tx] = Wc[(size_t)(m0 + ty + k * 8) * HD + d0 + tx];
    __syncthreads();
    #pragma unroll
    for (int k = 0; k < 4; k++)
        WcT[(size_t)(d0 + ty + k * 8) * MD + m0 + tx] =
            __float2bfloat16(s[tx][ty + k * 8]);
}

// ---------------------------------------------------------------------------
// Kernel 1b: split We [HD][MD] f32 -> hi/lo bf16 (elementwise)
// ---------------------------------------------------------------------------
__global__ void k_split_we(const float* __restrict__ We,
                           short* __restrict__ hi, short* __restrict__ lo) {
    const int i = (blockIdx.x * 256 + threadIdx.x) * 4;
    float4 v = *(const float4*)&We[i];
    short4 h, l;
    split1(v.x, h.x, l.x);
    split1(v.y, h.y, l.y);
    split1(v.z, h.z, l.z);
    split1(v.w, h.w, l.w);
    *(short4*)&hi[i] = h;
    *(short4*)&lo[i] = l;
}

// ---------------------------------------------------------------------------
// Kernel 1c: transpose+split x [B][MD][T] f32 -> xT hi/lo [B][T][MD] bf16
// ---------------------------------------------------------------------------
__global__ void k_split_x(const float* __restrict__ x,
                          short* __restrict__ xThi, short* __restrict__ xTlo) {
    __shared__ float s[32][33];
    const int t0 = blockIdx.x * 32;
    const int c0 = blockIdx.y * 32;
    const int b  = blockIdx.z;
    const int tx = threadIdx.x;   // 0..31
    const int ty = threadIdx.y;   // 0..7
    const float* xb = x + (size_t)b * MD * T_;
    #pragma unroll
    for (int k = 0; k < 4; k++)
        s[ty + k * 8][tx] = xb[(size_t)(c0 + ty + k * 8) * T_ + t0 + tx];
    __syncthreads();
    #pragma unroll
    for (int k = 0; k < 4; k++) {
        short h, l;
        split1(s[tx][ty + k * 8], h, l);
        const size_t o = ((size_t)b * T_ + t0 + ty + k * 8) * MD + c0 + tx;
        xThi[o] = h;
        xTlo[o] = l;
    }
}

// ---------------------------------------------------------------------------
// Kernel 2: expand GEMM via split-bf16 MFMA (3 passes: hh + hl + lh)
// y[b,d,t] = sum_c We[d,c]*x[b,c,t] + be[d], ~fp32 accuracy.
// 128x128 tile, BK=32, 4 waves of 4x4 16x16x32 tiles, global_load_lds 16B.
// ---------------------------------------------------------------------------
__launch_bounds__(256)
__global__ void k_gemm_mfma(const short* __restrict__ xThi,
                            const short* __restrict__ xTlo,
                            const short* __restrict__ Wehi,
                            const short* __restrict__ Welo,
                            const float* __restrict__ be,
                            float* __restrict__ y) {
    __shared__ __align__(16) short Ah[128 * 32];
    __shared__ __align__(16) short Al[128 * 32];
    __shared__ __align__(16) short Bh[128 * 32];
    __shared__ __align__(16) short Bl[128 * 32];

    const int t0  = blockIdx.x * 128;
    const int d0  = blockIdx.y * 128;
    const int b   = blockIdx.z;
    const int tid = threadIdx.x;
    const int lane = tid & 63;
    const int wave = tid >> 6;
    const int wm = wave >> 1, wn = wave & 1;
    const int fm = lane & 15, fq = lane >> 4;

    const short* A_h = Wehi + (size_t)d0 * MD;
    const short* A_l = Welo + (size_t)d0 * MD;
    const short* B_h = xThi + ((size_t)b * T_ + t0) * MD;
    const short* B_l = xTlo + ((size_t)b * T_ + t0) * MD;

    f32x4 acc[4][4];
    #pragma unroll
    for (int i = 0; i < 4; i++)
        #pragma unroll
        for (int j = 0; j < 4; j++) acc[i][j] = (f32x4)0.f;

    for (int k0 = 0; k0 < MD; k0 += 32) {
        #pragma unroll
        for (int i = 0; i < 2; i++) {
            const int e   = i * 256 + tid;
            const int row = e >> 2, kc = (e & 3) << 3;
            const size_t go = (size_t)row * MD + k0 + kc;
            const int lo = e << 3;   // shorts
            gload_lds16(A_h + go, &Ah[lo]);
            gload_lds16(A_l + go, &Al[lo]);
            gload_lds16(B_h + go, &Bh[lo]);
            gload_lds16(B_l + go, &Bl[lo]);
        }
        __syncthreads();

        short8 ah[4], al[4], bh[4], bl[4];
        #pragma unroll
        for (int mt = 0; mt < 4; mt++) {
            const int r = wm * 64 + mt * 16 + fm;
            ah[mt] = *(const short8*)&Ah[r * 32 + fq * 8];
            al[mt] = *(const short8*)&Al[r * 32 + fq * 8];
        }
        #pragma unroll
        for (int nt = 0; nt < 4; nt++) {
            const int r = wn * 64 + nt * 16 + fm;
            bh[nt] = *(const short8*)&Bh[r * 32 + fq * 8];
            bl[nt] = *(const short8*)&Bl[r * 32 + fq * 8];
        }
        #pragma unroll
        for (int mt = 0; mt < 4; mt++)
            #pragma unroll
            for (int nt = 0; nt < 4; nt++) {
                acc[mt][nt] = __builtin_amdgcn_mfma_f32_16x16x32_bf16(
                    ah[mt], bh[nt], acc[mt][nt], 0, 0, 0);
                acc[mt][nt] = __builtin_amdgcn_mfma_f32_16x16x32_bf16(
                    ah[mt], bl[nt], acc[mt][nt], 0, 0, 0);
                acc[mt][nt] = __builtin_amdgcn_mfma_f32_16x16x32_bf16(
                    al[mt], bh[nt], acc[mt][nt], 0, 0, 0);
            }
        __syncthreads();
    }

    // epilogue: C/D layout col=lane&15 (t), row=fq*4+r (d)
    float* yb = y + (size_t)b * HD * T_;
    #pragma unroll
    for (int mt = 0; mt < 4; mt++) {
        #pragma unroll
        for (int r = 0; r < 4; r++) {
            const int d = d0 + wm * 64 + mt * 16 + fq * 4 + r;
            const float bias = be[d];
            float* yd = yb + (size_t)d * T_ + t0 + wn * 64 + fm;
            #pragma unroll
            for (int nt = 0; nt < 4; nt++)
                yd[nt * 16] = acc[mt][nt][r] + bias;
        }
    }
}

// ---------------------------------------------------------------------------
// Kernel 3: exact top-64 per row of 4096. fp32 radix-select for the 64th
// value, then fp64 refinement of the boundary band so the selection matches
// the exact (reference) ordering. Tie-break lowest index. In-place sparsify
// + build per-(b,t) column lists of (d, val).
// ---------------------------------------------------------------------------
__launch_bounds__(256)
__global__ void k_topk(float* __restrict__ y,
                       const float* __restrict__ x,
                       const float* __restrict__ We,
                       const float* __restrict__ be,
                       int* __restrict__ colcnt, float2* __restrict__ collist) {
    __shared__ __align__(16) uint32_t su[T_];
    __shared__ double s_red[256];
    __shared__ double s_cand_val[64];
    __shared__ int    s_cand_idx[64];
    __shared__ unsigned char s_cand_keep[64];
    __shared__ int hist[16];
    __shared__ int s_bcast[2];
    __shared__ int s_nc, s_nhi;

    const int row = blockIdx.x;
    const int b   = row >> 11;
    const int d   = row & 2047;
    const int tid = threadIdx.x;
    float* yrow = y + (size_t)row * T_;

    #pragma unroll
    for (int j = 0; j < 4; j++) {
        const int i4 = j * 256 + tid;
        float4 v = *(const float4*)&yrow[i4 * 4];
        uint4 u;
        const uint32_t* pv = (const uint32_t*)&v;
        uint32_t* pu = (uint32_t*)&u;
        #pragma unroll
        for (int e = 0; e < 4; e++) {
            const uint32_t f = pv[e];
            pu[e] = (f & 0x80000000u) ? ~f : (f | 0x80000000u);
        }
        *(uint4*)&su[i4 * 4] = u;
    }

    uint32_t prefix = 0;
    int need = KEEP_;
    for (int shift = 28; shift >= 0; shift -= 4) {
        if (tid < 16) hist[tid] = 0;
        __syncthreads();
        #pragma unroll
        for (int j = 0; j < 16; j++) {
            const uint32_t u = su[j * 256 + tid];
            const uint32_t hi = (shift == 28) ? 0u : (u >> (shift + 4));
            if (hi == prefix) atomicAdd(&hist[(u >> shift) & 15], 1);
        }
        __syncthreads();
        if (tid == 0) {
            int cum = 0, chosen = 15;
            for (int bkt = 15; bkt >= 0; bkt--) {
                if (cum + hist[bkt] >= need) { chosen = bkt; break; }
                cum += hist[bkt];
            }
            s_bcast[0] = chosen;
            s_bcast[1] = need - cum;
        }
        __syncthreads();
        prefix = (prefix << 4) | (uint32_t)s_bcast[0];
        need = s_bcast[1];
    }
    const uint32_t Vu = prefix;
    const uint32_t Vb = (Vu & 0x80000000u) ? (Vu & 0x7FFFFFFFu) : ~Vu;
    const float Vf = __uint_as_float(Vb);
    const float hi_thr = Vf + BAND;
    const float lo_thr = Vf - BAND;

    if (tid == 0) { s_nc = 0; s_nhi = 0; }
    __syncthreads();
    #pragma unroll
    for (int j = 0; j < 16; j++) {
        const int i = j * 256 + tid;
        const uint32_t u = su[i];
        const uint32_t fb = (u & 0x80000000u) ? (u & 0x7FFFFFFFu) : ~u;
        const float f = __uint_as_float(fb);
        if (f > hi_thr) {
            atomicAdd(&s_nhi, 1);
        } else if (f >= lo_thr) {
            const int p = atomicAdd(&s_nc, 1);
            if (p < 64) s_cand_idx[p] = i;
        }
    }
    __syncthreads();
    const int nc    = min(s_nc, 64);
    const int slots = KEEP_ - s_nhi;

    if (nc > slots) {
        for (int j = 0; j < nc; j++) {
            const int t = s_cand_idx[j];
            double partial = 0.0;
            for (int c = tid; c < MD; c += 256)
                partial += (double)We[(size_t)d * MD + c] *
                           (double)x[((size_t)b * MD + c) * T_ + t];
            s_red[tid] = partial;
            __syncthreads();
            for (int off = 128; off > 0; off >>= 1) {
                if (tid < off) s_red[tid] += s_red[tid + off];
                __syncthreads();
            }
            if (tid == 0) s_cand_val[j] = s_red[0] + (double)be[d];
            __syncthreads();
        }
        if (tid < nc) {
            const double v = s_cand_val[tid];
            const int    ti = s_cand_idx[tid];
            int rank = 0;
            for (int j = 0; j < nc; j++) {
                if (j == tid) continue;
                if (s_cand_val[j] > v ||
                    (s_cand_val[j] == v && s_cand_idx[j] < ti)) rank++;
            }
            s_cand_keep[tid] = (rank < slots) ? 1 : 0;
        }
    } else {
        if (tid < nc) s_cand_keep[tid] = 1;
    }
    __syncthreads();

    #pragma unroll
    for (int j = 0; j < 16; j++) {
        const int i = j * 256 + tid;
        const uint32_t u = su[i];
        const uint32_t fb = (u & 0x80000000u) ? (u & 0x7FFFFFFFu) : ~u;
        const float f = __uint_as_float(fb);
        bool keep;
        if (f > hi_thr) {
            keep = true;
        } else if (f < lo_thr) {
            keep = false;
        } else {
            keep = false;
            for (int q = 0; q < nc; q++)
                if (s_cand_idx[q] == i) { keep = (s_cand_keep[q] != 0); break; }
        }
        if (keep) {
            const int col = b * T_ + i;
            const int pos = atomicAdd(&colcnt[col], 1);
            if (pos < CAP)
                collist[(size_t)col * CAP + pos] = make_float2(__int_as_float(d), f);
            yrow[i] = f;
        } else {
            yrow[i] = 0.0f;
        }
    }
}

// ---------------------------------------------------------------------------
// Kernel 4: sparse contract  out[b,m,t] = bc[m] + sum_nnz val * WcT[d][m]
// ---------------------------------------------------------------------------
__launch_bounds__(256)
__global__ void k_contract(const int* __restrict__ colcnt,
                           const float2* __restrict__ collist,
                           const __hip_bfloat16* __restrict__ WcT,
                           const float* __restrict__ bc,
                           float* __restrict__ out) {
    __shared__ float2 s_list[16][CAP];
    __shared__ int    s_cnt[16];
    __shared__ float  s_t[256][17];

    const int t0  = blockIdx.x * 16;
    const int b   = blockIdx.y;
    const int tid = threadIdx.x;

    if (tid < 16) s_cnt[tid] = min(colcnt[b * T_ + t0 + tid], CAP);
    __syncthreads();
    for (int c = 0; c < 16; c++) {
        const int n = s_cnt[c];
        for (int i = tid; i < n; i += 256)
            s_list[c][i] = collist[(size_t)(b * T_ + t0 + c) * CAP + i];
    }
    __syncthreads();

    for (int mc = 0; mc < 4; mc++) {
        const int m = mc * 256 + tid;
        const float bias = bc[m];
        float acc[16];
        #pragma unroll
        for (int c = 0; c < 16; c++) acc[c] = bias;

        for (int c = 0; c < 16; c++) {
            const int n = s_cnt[c];
            for (int i = 0; i < n; i++) {
                const float2 e = s_list[c][i];
                const int dd = __float_as_int(e.x);
                const float w = __bfloat162float(WcT[(size_t)dd * MD + m]);
                acc[c] = fmaf(e.y, w, acc[c]);
            }
        }

        #pragma unroll
        for (int c = 0; c < 16; c++) s_t[tid][c] = acc[c];
        __syncthreads();
        #pragma unroll
        for (int pass = 0; pass < 4; pass++) {
            const int r  = pass * 64 + (tid >> 2);
            const int cj = (tid & 3) * 4;
            float4 v;
            v.x = s_t[r][cj + 0];
            v.y = s_t[r][cj + 1];
            v.z = s_t[r][cj + 2];
            v.w = s_t[r][cj + 3];
            const int m_out = mc * 256 + r;
            *(float4*)&out[((size_t)b * MD + m_out) * T_ + t0 + cj] = v;
        }
        __syncthreads();
    }
}

// ---------------------------------------------------------------------------
extern "C" void kernel_launch(void* const* d_in, const int* in_sizes, int n_in,
                              void* d_out, int out_size, void* d_ws, size_t ws_size,
                              hipStream_t stream) {
    const float* x  = (const float*)d_in[0];   // [B, MD, T]
    const float* We = (const float*)d_in[1];   // [HD, MD]
    const float* be = (const float*)d_in[2];   // [HD]
    const float* Wc = (const float*)d_in[3];   // [MD, HD]
    const float* bc = (const float*)d_in[4];   // [MD]

    float* out0 = (float*)d_out;                        // out    [B, MD, T] (128MB)
    float* out1 = out0 + (size_t)B_ * MD * T_;          // sparse [B, HD, T] (256MB)

    // workspace layout: colcnt (128KB) | collist (24MB) | WcT bf16 (4MB)
    char* ws = (char*)d_ws;
    int*     colcnt  = (int*)ws;
    float2*  collist = (float2*)(ws + (size_t)B_ * T_ * sizeof(int));
    __hip_bfloat16* WcT =
        (__hip_bfloat16*)(ws + (size_t)B_ * T_ * sizeof(int) +
                          (size_t)B_ * T_ * CAP * sizeof(float2));

    // Aliasing (zero extra workspace):
    //  - xT hi/lo (2 x 64MB bf16) live in out0's 128MB, overwritten by contract.
    //  - We hi/lo (2 x 4MB bf16) live in collist's 24MB, overwritten by topk.
    short* xThi = (short*)out0;
    short* xTlo = xThi + (size_t)B_ * T_ * MD;
    short* Wehi = (short*)collist;
    short* Welo = Wehi + (size_t)HD * MD;

    hipMemsetAsync(colcnt, 0, (size_t)B_ * T_ * sizeof(int), stream);

    k_transpose_wc<<<dim3(HD / 32, MD / 32), dim3(32, 8), 0, stream>>>(Wc, WcT);
    k_split_we<<<(HD * MD) / 1024, 256, 0, stream>>>(We, Wehi, Welo);
    k_split_x<<<dim3(T_ / 32, MD / 32, B_), dim3(32, 8), 0, stream>>>(x, xThi, xTlo);
    k_gemm_mfma<<<dim3(T_ / 128, HD / 128, B_), 256, 0, stream>>>(
        xThi, xTlo, Wehi, Welo, be, out1);
    k_topk<<<B_ * HD, 256, 0, stream>>>(out1, x, We, be, colcnt, collist);
    k_contract<<<dim3(T_ / 16, B_), 256, 0, stream>>>(colcnt, collist, WcT, bc, out0);
}

// Round 4
// 1395.502 us; speedup vs baseline: 1.7748x; 1.0984x over previous
//
#include <hip/hip_runtime.h>
#include <hip/hip_bf16.h>
#include <stdint.h>

// Problem constants
#define B_    8
#define MD    1024   // MODEL_DIM
#define HD    2048   // HIGH_DIM
#define T_    4096
#define KEEP_ 64
#define CAP   96     // per-column nnz capacity (mean 32; P(>96) ~ 1e-18)
#define BAND  2e-4f  // top-k boundary band half-width (>> split-bf16 GEMM error ~1e-5)
#define NCAND 512    // candidate list capacity for threshold top-k

typedef __attribute__((ext_vector_type(8))) short short8;
typedef __attribute__((ext_vector_type(4))) float f32x4;

// async global->LDS, 16B per lane (wave-uniform LDS base + lane*16)
__device__ __forceinline__ void gload_lds16(const void* g, void* l) {
    __builtin_amdgcn_global_load_lds(
        (const __attribute__((address_space(1))) uint32_t*)g,
        (__attribute__((address_space(3))) uint32_t*)l, 16, 0, 0);
}

__device__ __forceinline__ void split1(float a, short& h, short& l) {
    __hip_bfloat16 bh = __float2bfloat16(a);
    float r = a - __bfloat162float(bh);
    __hip_bfloat16 bl = __float2bfloat16(r);
    h = *(short*)&bh;
    l = *(short*)&bl;
}

__device__ __forceinline__ uint32_t sortable(float f) {
    uint32_t u = __float_as_uint(f);
    return (u & 0x80000000u) ? ~u : (u | 0x80000000u);
}

// ---------------------------------------------------------------------------
// Kernel 1: transpose W_c [MD][HD] f32 -> W_cT [HD][MD] bf16 (L2-resident 4MB)
// ---------------------------------------------------------------------------
__global__ void k_transpose_wc(const float* __restrict__ Wc,
                               __hip_bfloat16* __restrict__ WcT) {
    __shared__ float s[32][33];
    const int d0 = blockIdx.x * 32;
    const int m0 = blockIdx.y * 32;
    const int tx = threadIdx.x;   // 0..31
    const int ty = threadIdx.y;   // 0..7
    #pragma unroll
    for (int k = 0; k < 4; k++)
        s[ty + k * 8][tx] = Wc[(size_t)(m0 + ty + k * 8) * HD + d0 + tx];
    __syncthreads();
    #pragma unroll
    for (int k = 0; k < 4; k++)
        WcT[(size_t)(d0 + ty + k * 8) * MD + m0 + tx] =
            __float2bfloat16(s[tx][ty + k * 8]);
}

// ---------------------------------------------------------------------------
// Kernel 1b: split We [HD][MD] f32 -> hi/lo bf16 (elementwise)
// ---------------------------------------------------------------------------
__global__ void k_split_we(const float* __restrict__ We,
                           short* __restrict__ hi, short* __restrict__ lo) {
    const int i = (blockIdx.x * 256 + threadIdx.x) * 4;
    float4 v = *(const float4*)&We[i];
    short4 h, l;
    split1(v.x, h.x, l.x);
    split1(v.y, h.y, l.y);
    split1(v.z, h.z, l.z);
    split1(v.w, h.w, l.w);
    *(short4*)&hi[i] = h;
    *(short4*)&lo[i] = l;
}

// ---------------------------------------------------------------------------
// Kernel 1c: transpose+split x [B][MD][T] f32 -> xT hi/lo [B][T][MD] bf16
// short4-vectorized stores.
// ---------------------------------------------------------------------------
__global__ void k_split_x(const float* __restrict__ x,
                          short* __restrict__ xThi, short* __restrict__ xTlo) {
    __shared__ float s[32][33];   // [c_local][t_local]
    const int t0 = blockIdx.x * 32;
    const int c0 = blockIdx.y * 32;
    const int b  = blockIdx.z;
    const int tx = threadIdx.x;   // 0..31
    const int ty = threadIdx.y;   // 0..7
    const float* xb = x + (size_t)b * MD * T_;
    #pragma unroll
    for (int k = 0; k < 4; k++)
        s[ty + k * 8][tx] = xb[(size_t)(c0 + ty + k * 8) * T_ + t0 + tx];
    __syncthreads();
    const int id = ty * 32 + tx;     // 0..255
    const int tl = id >> 3;          // t_local 0..31
    const int c4 = (id & 7) * 4;     // c_local group
    short4 h4, l4;
    split1(s[c4 + 0][tl], h4.x, l4.x);
    split1(s[c4 + 1][tl], h4.y, l4.y);
    split1(s[c4 + 2][tl], h4.z, l4.z);
    split1(s[c4 + 3][tl], h4.w, l4.w);
    const size_t o = ((size_t)b * T_ + t0 + tl) * MD + c0 + c4;
    *(short4*)&xThi[o] = h4;
    *(short4*)&xTlo[o] = l4;
}

// ---------------------------------------------------------------------------
// Kernel 2: expand GEMM via split-bf16 MFMA (3 passes: hh + hl + lh)
// 128x128 tile, BK=32, 4 waves of 4x4 16x16x32 tiles, global_load_lds 16B.
// ---------------------------------------------------------------------------
__launch_bounds__(256)
__global__ void k_gemm_mfma(const short* __restrict__ xThi,
                            const short* __restrict__ xTlo,
                            const short* __restrict__ Wehi,
                            const short* __restrict__ Welo,
                            const float* __restrict__ be,
                            float* __restrict__ y) {
    __shared__ __align__(16) short Ah[128 * 32];
    __shared__ __align__(16) short Al[128 * 32];
    __shared__ __align__(16) short Bh[128 * 32];
    __shared__ __align__(16) short Bl[128 * 32];

    const int t0  = blockIdx.x * 128;
    const int d0  = blockIdx.y * 128;
    const int b   = blockIdx.z;
    const int tid = threadIdx.x;
    const int lane = tid & 63;
    const int wave = tid >> 6;
    const int wm = wave >> 1, wn = wave & 1;
    const int fm = lane & 15, fq = lane >> 4;

    const short* A_h = Wehi + (size_t)d0 * MD;
    const short* A_l = Welo + (size_t)d0 * MD;
    const short* B_h = xThi + ((size_t)b * T_ + t0) * MD;
    const short* B_l = xTlo + ((size_t)b * T_ + t0) * MD;

    f32x4 acc[4][4];
    #pragma unroll
    for (int i = 0; i < 4; i++)
        #pragma unroll
        for (int j = 0; j < 4; j++) acc[i][j] = (f32x4)0.f;

    for (int k0 = 0; k0 < MD; k0 += 32) {
        #pragma unroll
        for (int i = 0; i < 2; i++) {
            const int e   = i * 256 + tid;
            const int row = e >> 2, kc = (e & 3) << 3;
            const size_t go = (size_t)row * MD + k0 + kc;
            const int lo = e << 3;   // shorts
            gload_lds16(A_h + go, &Ah[lo]);
            gload_lds16(A_l + go, &Al[lo]);
            gload_lds16(B_h + go, &Bh[lo]);
            gload_lds16(B_l + go, &Bl[lo]);
        }
        __syncthreads();

        short8 ah[4], al[4], bh[4], bl[4];
        #pragma unroll
        for (int mt = 0; mt < 4; mt++) {
            const int r = wm * 64 + mt * 16 + fm;
            ah[mt] = *(const short8*)&Ah[r * 32 + fq * 8];
            al[mt] = *(const short8*)&Al[r * 32 + fq * 8];
        }
        #pragma unroll
        for (int nt = 0; nt < 4; nt++) {
            const int r = wn * 64 + nt * 16 + fm;
            bh[nt] = *(const short8*)&Bh[r * 32 + fq * 8];
            bl[nt] = *(const short8*)&Bl[r * 32 + fq * 8];
        }
        #pragma unroll
        for (int mt = 0; mt < 4; mt++)
            #pragma unroll
            for (int nt = 0; nt < 4; nt++) {
                acc[mt][nt] = __builtin_amdgcn_mfma_f32_16x16x32_bf16(
                    ah[mt], bh[nt], acc[mt][nt], 0, 0, 0);
                acc[mt][nt] = __builtin_amdgcn_mfma_f32_16x16x32_bf16(
                    ah[mt], bl[nt], acc[mt][nt], 0, 0, 0);
                acc[mt][nt] = __builtin_amdgcn_mfma_f32_16x16x32_bf16(
                    al[mt], bh[nt], acc[mt][nt], 0, 0, 0);
            }
        __syncthreads();
    }

    // epilogue: C/D layout col=lane&15 (t), row=fq*4+r (d)
    float* yb = y + (size_t)b * HD * T_;
    #pragma unroll
    for (int mt = 0; mt < 4; mt++) {
        #pragma unroll
        for (int r = 0; r < 4; r++) {
            const int d = d0 + wm * 64 + mt * 16 + fq * 4 + r;
            const float bias = be[d];
            float* yd = yb + (size_t)d * T_ + t0 + wn * 64 + fm;
            #pragma unroll
            for (int nt = 0; nt < 4; nt++)
                yd[nt * 16] = acc[mt][nt][r] + bias;
        }
    }
}

// ---------------------------------------------------------------------------
// Kernel 3 (v2): exact top-64 per row of 4096 via statistics-guided
// threshold + exact candidate ranking (no radix, no histogram atomics).
// Row ~ N(mu, sd): collect ~140 candidates >= mu+1.8sd, rank exactly with
// index tie-break -> exact 64th value V. Then band classification + fp64
// refinement of in-band elements (identical selection semantics to radix
// version). In-place sparsify + per-(b,t) column lists.
// ---------------------------------------------------------------------------
__launch_bounds__(256)
__global__ void k_topk(float* __restrict__ y,
                       const float* __restrict__ x,
                       const float* __restrict__ We,
                       const float* __restrict__ be,
                       int* __restrict__ colcnt, float2* __restrict__ collist) {
    __shared__ double s_redd[256];          // fp64 reduction scratch
    __shared__ float  s_fred[8];
    __shared__ int    s_ired[8];
    __shared__ uint32_t s_cu[NCAND];
    __shared__ int      s_ci[NCAND];
    __shared__ int s_n;
    __shared__ uint32_t s_Vu;
    __shared__ int s_bidx[64];
    __shared__ uint32_t s_bu[64];
    __shared__ double s_bval[64];
    __shared__ unsigned char s_bkeep[64];
    __shared__ int s_nhi, s_nb;

    const int row  = blockIdx.x;
    const int b    = row >> 11;
    const int d    = row & 2047;
    const int tid  = threadIdx.x;
    const int lane = tid & 63;
    const int wave = tid >> 6;
    float* yrow = y + (size_t)row * T_;

    // ---- load 16 values/thread into registers ----
    float4 fv[4];
    #pragma unroll
    for (int j = 0; j < 4; j++)
        fv[j] = *(const float4*)&yrow[(j * 256 + tid) * 4];

    // ---- row stats (mu, sd) ----
    float s1 = 0.f, s2 = 0.f;
    #pragma unroll
    for (int j = 0; j < 4; j++) {
        const float* p = (const float*)&fv[j];
        #pragma unroll
        for (int e = 0; e < 4; e++) { s1 += p[e]; s2 = fmaf(p[e], p[e], s2); }
    }
    for (int off = 32; off > 0; off >>= 1) {
        s1 += __shfl_down(s1, off);
        s2 += __shfl_down(s2, off);
    }
    if (lane == 0) { s_fred[wave] = s1; s_fred[4 + wave] = s2; }
    __syncthreads();
    const float S1 = s_fred[0] + s_fred[1] + s_fred[2] + s_fred[3];
    const float S2 = s_fred[4] + s_fred[5] + s_fred[6] + s_fred[7];
    const float mu = S1 * (1.f / T_);
    const float sd = sqrtf(fmaxf(S2 * (1.f / T_) - mu * mu, 1e-20f));

    // ---- find threshold with KEEP <= count <= NCAND ----
    float thr = mu + 1.8f * sd;
    int total = 0;
    for (int iter = 0; iter < 16; iter++) {
        int c = 0;
        #pragma unroll
        for (int j = 0; j < 4; j++) {
            const float* p = (const float*)&fv[j];
            #pragma unroll
            for (int e = 0; e < 4; e++) c += (p[e] >= thr);
        }
        for (int off = 32; off > 0; off >>= 1) c += __shfl_down(c, off);
        __syncthreads();               // protect s_ired reuse
        if (lane == 0) s_ired[wave] = c;
        __syncthreads();
        total = s_ired[0] + s_ired[1] + s_ired[2] + s_ired[3];
        if (total >= KEEP_ && total <= NCAND) break;
        thr += (total < KEEP_) ? (-0.3f * sd) : (0.3f * sd);
    }

    // ---- collect candidates ----
    if (tid == 0) { s_n = 0; s_Vu = 0; }
    __syncthreads();
    #pragma unroll
    for (int j = 0; j < 4; j++) {
        const float* p = (const float*)&fv[j];
        #pragma unroll
        for (int e = 0; e < 4; e++) {
            if (p[e] >= thr) {
                const int pos = atomicAdd(&s_n, 1);
                if (pos < NCAND) {
                    s_cu[pos] = sortable(p[e]);
                    s_ci[pos] = (j * 256 + tid) * 4 + e;
                }
            }
        }
    }
    __syncthreads();
    int nc = min(s_n, NCAND);

    // ---- exact rank: find 64th-largest (ties -> lower index wins) ----
    for (int ci = tid; ci < nc; ci += 256) {
        const uint32_t u = s_cu[ci];
        const int id = s_ci[ci];
        int r = 0;
        for (int j = 0; j < nc; j++) {
            const uint32_t uj = s_cu[j];
            r += (uj > u) || (uj == u && s_ci[j] < id);
        }
        if (r == KEEP_ - 1) s_Vu = u;
    }
    __syncthreads();
    const uint32_t Vu = s_Vu;
    const uint32_t Vb = (Vu & 0x80000000u) ? (Vu & 0x7FFFFFFFu) : ~Vu;
    const float Vf = __uint_as_float(Vb);
    const float hi_thr = Vf + BAND;
    const float lo_thr = Vf - BAND;
    const uint32_t hiU = sortable(hi_thr);
    const uint32_t loU = sortable(lo_thr);

    // ---- ensure band completeness: recollect if lo_thr below threshold ----
    if (lo_thr < thr) {
        __syncthreads();
        if (tid == 0) s_n = 0;
        __syncthreads();
        #pragma unroll
        for (int j = 0; j < 4; j++) {
            const float* p = (const float*)&fv[j];
            #pragma unroll
            for (int e = 0; e < 4; e++) {
                if (p[e] >= lo_thr) {
                    const int pos = atomicAdd(&s_n, 1);
                    if (pos < NCAND) {
                        s_cu[pos] = sortable(p[e]);
                        s_ci[pos] = (j * 256 + tid) * 4 + e;
                    }
                }
            }
        }
        __syncthreads();
        nc = min(s_n, NCAND);
    }

    // ---- classify candidates: count > hi band, collect in-band ----
    if (tid == 0) { s_nhi = 0; s_nb = 0; }
    __syncthreads();
    for (int ci = tid; ci < nc; ci += 256) {
        const uint32_t u = s_cu[ci];
        if (u > hiU) {
            atomicAdd(&s_nhi, 1);
        } else if (u >= loU) {
            const int p = atomicAdd(&s_nb, 1);
            if (p < 64) { s_bidx[p] = s_ci[ci]; s_bu[p] = u; }
        }
    }
    __syncthreads();
    const int nb    = min(s_nb, 64);
    const int slots = KEEP_ - s_nhi;

    if (nb > slots) {
        // true near-tie: recompute in-band candidates in fp64, rank exactly
        for (int j = 0; j < nb; j++) {
            const int t = s_bidx[j];
            double partial = 0.0;
            for (int c = tid; c < MD; c += 256)
                partial += (double)We[(size_t)d * MD + c] *
                           (double)x[((size_t)b * MD + c) * T_ + t];
            s_redd[tid] = partial;
            __syncthreads();
            for (int off = 128; off > 0; off >>= 1) {
                if (tid < off) s_redd[tid] += s_redd[tid + off];
                __syncthreads();
            }
            if (tid == 0) s_bval[j] = s_redd[0] + (double)be[d];
            __syncthreads();
        }
        if (tid < nb) {
            const double v = s_bval[tid];
            const int    ti = s_bidx[tid];
            int rank = 0;
            for (int j = 0; j < nb; j++) {
                if (j == tid) continue;
                if (s_bval[j] > v ||
                    (s_bval[j] == v && s_bidx[j] < ti)) rank++;
            }
            s_bkeep[tid] = (rank < slots) ? 1 : 0;
        }
    } else {
        if (tid < nb) s_bkeep[tid] = 1;
    }
    __syncthreads();

    // ---- write back sparse row + scatter kept into column lists ----
    #pragma unroll
    for (int j = 0; j < 4; j++) {
        float* p = (float*)&fv[j];
        #pragma unroll
        for (int e = 0; e < 4; e++) {
            const int i = (j * 256 + tid) * 4 + e;
            const float f = p[e];
            const uint32_t u = sortable(f);
            bool keep;
            if (u > hiU) {
                keep = true;
            } else if (u < loU) {
                keep = false;
            } else {
                keep = false;
                for (int q = 0; q < nb; q++)
                    if (s_bidx[q] == i) { keep = (s_bkeep[q] != 0); break; }
            }
            if (keep) {
                const int col = b * T_ + i;
                const int pos = atomicAdd(&colcnt[col], 1);
                if (pos < CAP)
                    collist[(size_t)col * CAP + pos] =
                        make_float2(__int_as_float(d), f);
            } else {
                p[e] = 0.0f;
            }
        }
        *(float4*)&yrow[(j * 256 + tid) * 4] = fv[j];
    }
}

// ---------------------------------------------------------------------------
// Kernel 4: sparse contract  out[b,m,t] = bc[m] + sum_nnz val * WcT[d][m]
// nnz loop unrolled x4 with independent loads (break dep-latency chain).
// ---------------------------------------------------------------------------
__launch_bounds__(256)
__global__ void k_contract(const int* __restrict__ colcnt,
                           const float2* __restrict__ collist,
                           const __hip_bfloat16* __restrict__ WcT,
                           const float* __restrict__ bc,
                           float* __restrict__ out) {
    __shared__ float2 s_list[16][CAP];
    __shared__ int    s_cnt[16];
    __shared__ float  s_t[256][17];

    const int t0  = blockIdx.x * 16;
    const int b   = blockIdx.y;
    const int tid = threadIdx.x;

    if (tid < 16) s_cnt[tid] = min(colcnt[b * T_ + t0 + tid], CAP);
    __syncthreads();
    for (int c = 0; c < 16; c++) {
        const int n = s_cnt[c];
        for (int i = tid; i < n; i += 256)
            s_list[c][i] = collist[(size_t)(b * T_ + t0 + c) * CAP + i];
    }
    __syncthreads();

    for (int mc = 0; mc < 4; mc++) {
        const int m = mc * 256 + tid;
        const float bias = bc[m];
        float acc[16];
        #pragma unroll
        for (int c = 0; c < 16; c++) acc[c] = bias;

        #pragma unroll
        for (int c = 0; c < 16; c++) {
            const int n = s_cnt[c];
            float a = acc[c];
            int i = 0;
            for (; i + 4 <= n; i += 4) {
                const float2 e0 = s_list[c][i + 0];
                const float2 e1 = s_list[c][i + 1];
                const float2 e2 = s_list[c][i + 2];
                const float2 e3 = s_list[c][i + 3];
                const float w0 = __bfloat162float(
                    WcT[(size_t)__float_as_int(e0.x) * MD + m]);
                const float w1 = __bfloat162float(
                    WcT[(size_t)__float_as_int(e1.x) * MD + m]);
                const float w2 = __bfloat162float(
                    WcT[(size_t)__float_as_int(e2.x) * MD + m]);
                const float w3 = __bfloat162float(
                    WcT[(size_t)__float_as_int(e3.x) * MD + m]);
                a = fmaf(e0.y, w0, a);
                a = fmaf(e1.y, w1, a);
                a = fmaf(e2.y, w2, a);
                a = fmaf(e3.y, w3, a);
            }
            for (; i < n; i++) {
                const float2 e = s_list[c][i];
                const float w = __bfloat162float(
                    WcT[(size_t)__float_as_int(e.x) * MD + m]);
                a = fmaf(e.y, w, a);
            }
            acc[c] = a;
        }

        #pragma unroll
        for (int c = 0; c < 16; c++) s_t[tid][c] = acc[c];
        __syncthreads();
        #pragma unroll
        for (int pass = 0; pass < 4; pass++) {
            const int r  = pass * 64 + (tid >> 2);
            const int cj = (tid & 3) * 4;
            float4 v;
            v.x = s_t[r][cj + 0];
            v.y = s_t[r][cj + 1];
            v.z = s_t[r][cj + 2];
            v.w = s_t[r][cj + 3];
            const int m_out = mc * 256 + r;
            *(float4*)&out[((size_t)b * MD + m_out) * T_ + t0 + cj] = v;
        }
        __syncthreads();
    }
}

// ---------------------------------------------------------------------------
extern "C" void kernel_launch(void* const* d_in, const int* in_sizes, int n_in,
                              void* d_out, int out_size, void* d_ws, size_t ws_size,
                              hipStream_t stream) {
    const float* x  = (const float*)d_in[0];   // [B, MD, T]
    const float* We = (const float*)d_in[1];   // [HD, MD]
    const float* be = (const float*)d_in[2];   // [HD]
    const float* Wc = (const float*)d_in[3];   // [MD, HD]
    const float* bc = (const float*)d_in[4];   // [MD]

    float* out0 = (float*)d_out;                        // out    [B, MD, T] (128MB)
    float* out1 = out0 + (size_t)B_ * MD * T_;          // sparse [B, HD, T] (256MB)

    // workspace layout: colcnt (128KB) | collist (24MB) | WcT bf16 (4MB)
    char* ws = (char*)d_ws;
    int*     colcnt  = (int*)ws;
    float2*  collist = (float2*)(ws + (size_t)B_ * T_ * sizeof(int));
    __hip_bfloat16* WcT =
        (__hip_bfloat16*)(ws + (size_t)B_ * T_ * sizeof(int) +
                          (size_t)B_ * T_ * CAP * sizeof(float2));

    // Aliasing (zero extra workspace):
    //  - xT hi/lo (2 x 64MB bf16) live in out0's 128MB, overwritten by contract.
    //  - We hi/lo (2 x 4MB bf16) live in collist's 24MB, overwritten by topk.
    short* xThi = (short*)out0;
    short* xTlo = xThi + (size_t)B_ * T_ * MD;
    short* Wehi = (short*)collist;
    short* Welo = Wehi + (size_t)HD * MD;

    hipMemsetAsync(colcnt, 0, (size_t)B_ * T_ * sizeof(int), stream);

    k_transpose_wc<<<dim3(HD / 32, MD / 32), dim3(32, 8), 0, stream>>>(Wc, WcT);
    k_split_we<<<(HD * MD) / 1024, 256, 0, stream>>>(We, Wehi, Welo);
    k_split_x<<<dim3(T_ / 32, MD / 32, B_), dim3(32, 8), 0, stream>>>(x, xThi, xTlo);
    k_gemm_mfma<<<dim3(T_ / 128, HD / 128, B_), 256, 0, stream>>>(
        xThi, xTlo, Wehi, Welo, be, out1);
    k_topk<<<B_ * HD, 256, 0, stream>>>(out1, x, We, be, colcnt, collist);
    k_contract<<<dim3(T_ / 16, B_), 256, 0, stream>>>(colcnt, collist, WcT, bc, out0);
}